// Round 1
// baseline (1001.521 us; speedup 1.0000x reference)
//
#include <hip/hip_runtime.h>
#include <cstdint>
#include <cstddef>

// Problem constants (PairwiseConv_22488448761917)
#define BATCH   4
#define CIN     128
#define NN      4096
#define EE      131072
#define CCONV   127      // C_OUT - 1

// ---------------------------------------------------------------------------
// K1: transpose x (B, C, N) -> xT (B, N, C), tiled 32x32 via LDS
// ---------------------------------------------------------------------------
__global__ __launch_bounds__(256) void k_tx(const float* __restrict__ x,
                                            float* __restrict__ xT) {
    __shared__ float tile[32][33];
    const int b  = blockIdx.z;
    const int n0 = blockIdx.x * 32;
    const int c0 = blockIdx.y * 32;
    const int tx = threadIdx.x;   // 0..31
    const int ty = threadIdx.y;   // 0..7
    const float* xb = x + (size_t)b * CIN * NN;
#pragma unroll
    for (int i = 0; i < 4; ++i)
        tile[ty + i * 8][tx] = xb[(size_t)(c0 + ty + i * 8) * NN + n0 + tx];
    __syncthreads();
    float* xTb = xT + (size_t)b * NN * CIN;
#pragma unroll
    for (int i = 0; i < 4; ++i)
        xTb[(size_t)(n0 + ty + i * 8) * CIN + c0 + tx] = tile[tx][ty + i * 8];
}

// ---------------------------------------------------------------------------
// K2: build WT[k][o], k in [0,256): k<128 -> W[o][k][0], k>=128 -> W[o][k-128][1]
//     o==127 column zero-padded.
// ---------------------------------------------------------------------------
__global__ __launch_bounds__(256) void k_wt(const float* __restrict__ W,
                                            float* __restrict__ WT) {
    const int t = blockIdx.x * 256 + threadIdx.x;  // < 256*128
    const int k = t >> 7;
    const int o = t & 127;
    float v = 0.0f;
    if (o < CCONV) {
        const int c = k & 127;
        const int which = k >> 7;
        v = W[((size_t)o * CIN + c) * 2 + which];
    }
    WT[t] = v;
}

// ---------------------------------------------------------------------------
// K3: degree counts. cnt_i from idx_i (scatter target), deg from idx_j.
// ---------------------------------------------------------------------------
__global__ __launch_bounds__(256) void k_count(const int* __restrict__ idx_i,
                                               const int* __restrict__ idx_j,
                                               int* __restrict__ cnt_i,
                                               int* __restrict__ deg) {
    const int e = blockIdx.x * 256 + threadIdx.x;
    atomicAdd(&cnt_i[idx_i[e]], 1);
    atomicAdd(&deg[idx_j[e]], 1);
}

// ---------------------------------------------------------------------------
// K4: aggregation: agg[b, idx_i[e], :] += xT[b, idx_j[e], :]
//     32 lanes per edge, float4 gather, 4 scalar atomics per lane per batch.
// ---------------------------------------------------------------------------
__global__ __launch_bounds__(256) void k_agg(const float* __restrict__ xT,
                                             float* __restrict__ agg,
                                             const int* __restrict__ idx_i,
                                             const int* __restrict__ idx_j) {
    const int t  = blockIdx.x * 256 + threadIdx.x;
    const int e  = t >> 5;            // 32 lanes per edge
    const int cg = (t & 31) * 4;      // channel group (float4)
    const int ni = idx_i[e];
    const int nj = idx_j[e];
#pragma unroll
    for (int b = 0; b < BATCH; ++b) {
        const float4 v = *(const float4*)(xT + ((size_t)b * NN + nj) * CIN + cg);
        float* dst = agg + ((size_t)b * NN + ni) * CIN + cg;
        atomicAdd(dst + 0, v.x);
        atomicAdd(dst + 1, v.y);
        atomicAdd(dst + 2, v.z);
        atomicAdd(dst + 3, v.w);
    }
}

// ---------------------------------------------------------------------------
// K5: final fused GEMM + epilogue.
//   Z[k][j] (k in [0,256)): k<128 -> x[b][k][n0+j] * cnt_i[n0+j]
//                           k>=128 -> agg[b][n0+j][k-128]
//   out[b][o][n0+j] = (sum_k WT[k][o] Z[k][j] + cnt*bias[o]) * invdeg[j]
//   Block: 256 threads = 16(to) x 16(tn); thread tile 8o x 4n; n-tile 64.
// ---------------------------------------------------------------------------
__global__ __launch_bounds__(256) void k_final(const float* __restrict__ x,
                                               const float* __restrict__ WT,
                                               const float* __restrict__ bias,
                                               const float* __restrict__ agg,
                                               const int* __restrict__ cnt_i,
                                               const int* __restrict__ deg,
                                               float* __restrict__ out) {
    __shared__ float zs[256 * 65];   // padded stride 65: conflict-free
    __shared__ float cntf[64];
    __shared__ float invd[64];

    const int b   = blockIdx.y;
    const int n0  = blockIdx.x * 64;
    const int tid = threadIdx.x;

    if (tid < 64) {
        const int c = cnt_i[n0 + tid];
        const int d = deg[n0 + tid];
        cntf[tid] = (float)c;
        invd[tid] = (d == 0) ? 1.0f : 1.0f / (float)d;
    }
    __syncthreads();

    // Stage x-part (scaled by cnt) -- coalesced along n
    const float* xb = x + (size_t)b * CIN * NN;
    for (int idx = tid; idx < CIN * 64; idx += 256) {
        const int c = idx >> 6;
        const int j = idx & 63;
        zs[c * 65 + j] = xb[(size_t)c * NN + n0 + j] * cntf[j];
    }
    // Stage agg-part -- coalesced along c, transposed into k-major LDS
    const float* ab = agg + ((size_t)b * NN + n0) * CIN;
    for (int idx = tid; idx < 64 * CIN; idx += 256) {
        const int j = idx >> 7;
        const int c = idx & 127;
        zs[(128 + c) * 65 + j] = ab[(size_t)j * CIN + c];
    }
    __syncthreads();

    const int to = tid >> 4;   // 0..15 -> o base = to*8
    const int tn = tid & 15;   // 0..15 -> n base = tn*4

    float acc[8][4];
#pragma unroll
    for (int oi = 0; oi < 8; ++oi)
#pragma unroll
        for (int ni = 0; ni < 4; ++ni) acc[oi][ni] = 0.0f;

    for (int k = 0; k < 256; ++k) {
        const float4 wa = *(const float4*)(WT + (k << 7) + (to << 3));
        const float4 wb = *(const float4*)(WT + (k << 7) + (to << 3) + 4);
        const float w[8] = {wa.x, wa.y, wa.z, wa.w, wb.x, wb.y, wb.z, wb.w};
        float z[4];
#pragma unroll
        for (int ni = 0; ni < 4; ++ni) z[ni] = zs[k * 65 + (tn << 2) + ni];
#pragma unroll
        for (int oi = 0; oi < 8; ++oi)
#pragma unroll
            for (int ni = 0; ni < 4; ++ni) acc[oi][ni] += w[oi] * z[ni];
    }

    // Epilogue
    const float cn0 = cntf[tn * 4 + 0], cn1 = cntf[tn * 4 + 1],
                cn2 = cntf[tn * 4 + 2], cn3 = cntf[tn * 4 + 3];
    const float iv0 = invd[tn * 4 + 0], iv1 = invd[tn * 4 + 1],
                iv2 = invd[tn * 4 + 2], iv3 = invd[tn * 4 + 3];
#pragma unroll
    for (int oi = 0; oi < 8; ++oi) {
        const int o = to * 8 + oi;
        if (o >= CCONV) continue;   // channel 127 written by k_ch127
        const float bv = bias[o];
        float4 r;
        r.x = (acc[oi][0] + cn0 * bv) * iv0;
        r.y = (acc[oi][1] + cn1 * bv) * iv1;
        r.z = (acc[oi][2] + cn2 * bv) * iv2;
        r.w = (acc[oi][3] + cn3 * bv) * iv3;
        *(float4*)(out + ((size_t)b * 128 + o) * NN + n0 + tn * 4) = r;
    }
}

// ---------------------------------------------------------------------------
// K6: out[b][127][n] = deg[n]
// ---------------------------------------------------------------------------
__global__ __launch_bounds__(256) void k_ch127(const int* __restrict__ deg,
                                               float* __restrict__ out) {
    const int t = blockIdx.x * 256 + threadIdx.x;   // < BATCH*NN
    const int b = t >> 12;
    const int n = t & (NN - 1);
    out[((size_t)b * 128 + CCONV) * NN + n] = (float)deg[n];
}

// ---------------------------------------------------------------------------
extern "C" void kernel_launch(void* const* d_in, const int* in_sizes, int n_in,
                              void* d_out, int out_size, void* d_ws, size_t ws_size,
                              hipStream_t stream) {
    const float* x    = (const float*)d_in[0];
    const float* W    = (const float*)d_in[1];
    const float* bias = (const float*)d_in[2];
    const int* idx_i  = (const int*)d_in[3];
    const int* idx_j  = (const int*)d_in[4];
    float* out = (float*)d_out;

    // Workspace layout (bytes):
    //   agg   : 0          .. 8388608   (B*N*C f32)
    //   cnt_i : 8388608    .. 8404992   (N i32)
    //   deg   : 8404992    .. 8421376   (N i32)
    //   xT    : 8421376    .. 16809984  (B*N*C f32)
    //   WT    : 16809984   .. 16941056  (256*128 f32)
    char* ws = (char*)d_ws;
    float* agg  = (float*)(ws);
    int*   cnt  = (int*)(ws + 8388608);
    int*   deg  = (int*)(ws + 8404992);
    float* xT   = (float*)(ws + 8421376);
    float* WT   = (float*)(ws + 16809984);

    // Zero agg + cnt + deg (one contiguous region)
    hipMemsetAsync(agg, 0, 8421376, stream);

    k_tx<<<dim3(NN / 32, CIN / 32, BATCH), dim3(32, 8), 0, stream>>>(x, xT);
    k_wt<<<(256 * 128) / 256, 256, 0, stream>>>(W, WT);
    k_count<<<EE / 256, 256, 0, stream>>>(idx_i, idx_j, cnt, deg);
    k_agg<<<EE / 8, 256, 0, stream>>>(xT, agg, idx_i, idx_j);
    k_final<<<dim3(NN / 64, BATCH), 256, 0, stream>>>(x, WT, bias, agg, cnt, deg, out);
    k_ch127<<<(BATCH * NN) / 256, 256, 0, stream>>>(deg, out);
}

// Round 2
// 172.854 us; speedup vs baseline: 5.7940x; 5.7940x over previous
//
#include <hip/hip_runtime.h>
#include <cstdint>
#include <cstddef>

// Problem constants (PairwiseConv_22488448761917)
#define BATCH   4
#define CIN     128
#define NN      4096
#define EE      131072
#define CCONV   127      // C_OUT - 1

// ---------------------------------------------------------------------------
// K1: transpose x (B, C, N) -> xT (B, N, C), tiled 32x32 via LDS
// ---------------------------------------------------------------------------
__global__ __launch_bounds__(256) void k_tx(const float* __restrict__ x,
                                            float* __restrict__ xT) {
    __shared__ float tile[32][33];
    const int b  = blockIdx.z;
    const int n0 = blockIdx.x * 32;
    const int c0 = blockIdx.y * 32;
    const int tx = threadIdx.x;   // 0..31
    const int ty = threadIdx.y;   // 0..7
    const float* xb = x + (size_t)b * CIN * NN;
#pragma unroll
    for (int i = 0; i < 4; ++i)
        tile[ty + i * 8][tx] = xb[(size_t)(c0 + ty + i * 8) * NN + n0 + tx];
    __syncthreads();
    float* xTb = xT + (size_t)b * NN * CIN;
#pragma unroll
    for (int i = 0; i < 4; ++i)
        xTb[(size_t)(n0 + ty + i * 8) * CIN + c0 + tx] = tile[tx][ty + i * 8];
}

// ---------------------------------------------------------------------------
// K2: build WT[k][o], k in [0,256): k<128 -> W[o][k][0], k>=128 -> W[o][k-128][1]
//     o==127 column zero-padded. (Launched AFTER k_agg_csr: WT overlaps elist.)
// ---------------------------------------------------------------------------
__global__ __launch_bounds__(256) void k_wt(const float* __restrict__ W,
                                            float* __restrict__ WT) {
    const int t = blockIdx.x * 256 + threadIdx.x;  // < 256*128
    const int k = t >> 7;
    const int o = t & 127;
    float v = 0.0f;
    if (o < CCONV) {
        const int c = k & 127;
        const int which = k >> 7;
        v = W[((size_t)o * CIN + c) * 2 + which];
    }
    WT[t] = v;
}

// ---------------------------------------------------------------------------
// K3: degree counts. cnt_i from idx_i (scatter target), deg from idx_j.
// ---------------------------------------------------------------------------
__global__ __launch_bounds__(256) void k_count(const int* __restrict__ idx_i,
                                               const int* __restrict__ idx_j,
                                               int* __restrict__ cnt_i,
                                               int* __restrict__ deg) {
    const int e = blockIdx.x * 256 + threadIdx.x;
    atomicAdd(&cnt_i[idx_i[e]], 1);
    atomicAdd(&deg[idx_j[e]], 1);
}

// ---------------------------------------------------------------------------
// K3b: exclusive prefix scan of cnt_i[4096] -> start[4096]. Single block,
//      1024 threads x 4 elements, Hillis-Steele over 1024 partials in LDS.
// ---------------------------------------------------------------------------
__global__ __launch_bounds__(1024) void k_scan(const int* __restrict__ cnt,
                                               int* __restrict__ start) {
    __shared__ int sums[1024];
    const int tid = threadIdx.x;
    int v[4];
    int s = 0;
#pragma unroll
    for (int i = 0; i < 4; ++i) { v[i] = cnt[tid * 4 + i]; s += v[i]; }
    sums[tid] = s;
    __syncthreads();
    for (int off = 1; off < 1024; off <<= 1) {
        const int t = (tid >= off) ? sums[tid - off] : 0;
        __syncthreads();
        sums[tid] += t;
        __syncthreads();
    }
    int base = (tid == 0) ? 0 : sums[tid - 1];
#pragma unroll
    for (int i = 0; i < 4; ++i) { start[tid * 4 + i] = base; base += v[i]; }
}

// ---------------------------------------------------------------------------
// K3c: scatter edges into CSR lists: elist[start[ni] + pos] = nj (ushort).
// ---------------------------------------------------------------------------
__global__ __launch_bounds__(256) void k_scatter(const int* __restrict__ idx_i,
                                                 const int* __restrict__ idx_j,
                                                 const int* __restrict__ start,
                                                 int* __restrict__ cursor,
                                                 unsigned short* __restrict__ elist) {
    const int e = blockIdx.x * 256 + threadIdx.x;
    const int ni = idx_i[e];
    const int pos = atomicAdd(&cursor[ni], 1);
    elist[start[ni] + pos] = (unsigned short)idx_j[e];
}

// ---------------------------------------------------------------------------
// K4: CSR aggregation (NO float atomics):
//     agg[b, n, :] = sum over edges e with idx_i[e]==n of xT[b, idx_j[e], :]
//     One block per node n; 256 threads = 4 batches x 64 lanes x float2.
// ---------------------------------------------------------------------------
__global__ __launch_bounds__(256) void k_agg_csr(const float* __restrict__ xT,
                                                 const int* __restrict__ start,
                                                 const int* __restrict__ cnt,
                                                 const unsigned short* __restrict__ elist,
                                                 float* __restrict__ agg) {
    const int n   = blockIdx.x;
    const int tid = threadIdx.x;
    const int b   = tid >> 6;          // 0..3
    const int c2  = (tid & 63) << 1;   // channel pair base
    const int s0  = start[n];
    const int dn  = cnt[n];
    const float* xb = xT + (size_t)b * NN * CIN + c2;
    float2 acc = {0.0f, 0.0f};
    int k = 0;
    for (; k + 2 <= dn; k += 2) {
        const int nj0 = elist[s0 + k];
        const int nj1 = elist[s0 + k + 1];
        const float2 v0 = *(const float2*)(xb + (size_t)nj0 * CIN);
        const float2 v1 = *(const float2*)(xb + (size_t)nj1 * CIN);
        acc.x += v0.x + v1.x;
        acc.y += v0.y + v1.y;
    }
    if (k < dn) {
        const int nj = elist[s0 + k];
        const float2 v = *(const float2*)(xb + (size_t)nj * CIN);
        acc.x += v.x;
        acc.y += v.y;
    }
    *(float2*)(agg + ((size_t)b * NN + n) * CIN + c2) = acc;
}

// ---------------------------------------------------------------------------
// K5: final fused GEMM + epilogue.
//   Z[k][j] (k in [0,256)): k<128 -> x[b][k][n0+j] * cnt_i[n0+j]
//                           k>=128 -> agg[b][n0+j][k-128]
//   out[b][o][n0+j] = (sum_k WT[k][o] Z[k][j] + cnt*bias[o]) * invdeg[j]
// ---------------------------------------------------------------------------
__global__ __launch_bounds__(256) void k_final(const float* __restrict__ x,
                                               const float* __restrict__ WT,
                                               const float* __restrict__ bias,
                                               const float* __restrict__ agg,
                                               const int* __restrict__ cnt_i,
                                               const int* __restrict__ deg,
                                               float* __restrict__ out) {
    __shared__ float zs[256 * 65];   // padded stride 65: conflict-free
    __shared__ float cntf[64];
    __shared__ float invd[64];

    const int b   = blockIdx.y;
    const int n0  = blockIdx.x * 64;
    const int tid = threadIdx.x;

    if (tid < 64) {
        const int c = cnt_i[n0 + tid];
        const int d = deg[n0 + tid];
        cntf[tid] = (float)c;
        invd[tid] = (d == 0) ? 1.0f : 1.0f / (float)d;
    }
    __syncthreads();

    const float* xb = x + (size_t)b * CIN * NN;
    for (int idx = tid; idx < CIN * 64; idx += 256) {
        const int c = idx >> 6;
        const int j = idx & 63;
        zs[c * 65 + j] = xb[(size_t)c * NN + n0 + j] * cntf[j];
    }
    const float* ab = agg + ((size_t)b * NN + n0) * CIN;
    for (int idx = tid; idx < 64 * CIN; idx += 256) {
        const int j = idx >> 7;
        const int c = idx & 127;
        zs[(128 + c) * 65 + j] = ab[(size_t)j * CIN + c];
    }
    __syncthreads();

    const int to = tid >> 4;   // o base = to*8
    const int tn = tid & 15;   // n base = tn*4

    float acc[8][4];
#pragma unroll
    for (int oi = 0; oi < 8; ++oi)
#pragma unroll
        for (int ni = 0; ni < 4; ++ni) acc[oi][ni] = 0.0f;

    for (int k = 0; k < 256; ++k) {
        const float4 wa = *(const float4*)(WT + (k << 7) + (to << 3));
        const float4 wb = *(const float4*)(WT + (k << 7) + (to << 3) + 4);
        const float w[8] = {wa.x, wa.y, wa.z, wa.w, wb.x, wb.y, wb.z, wb.w};
        float z[4];
#pragma unroll
        for (int ni = 0; ni < 4; ++ni) z[ni] = zs[k * 65 + (tn << 2) + ni];
#pragma unroll
        for (int oi = 0; oi < 8; ++oi)
#pragma unroll
            for (int ni = 0; ni < 4; ++ni) acc[oi][ni] += w[oi] * z[ni];
    }

    const float cn0 = cntf[tn * 4 + 0], cn1 = cntf[tn * 4 + 1],
                cn2 = cntf[tn * 4 + 2], cn3 = cntf[tn * 4 + 3];
    const float iv0 = invd[tn * 4 + 0], iv1 = invd[tn * 4 + 1],
                iv2 = invd[tn * 4 + 2], iv3 = invd[tn * 4 + 3];
#pragma unroll
    for (int oi = 0; oi < 8; ++oi) {
        const int o = to * 8 + oi;
        if (o >= CCONV) continue;   // channel 127 written by k_ch127
        const float bv = bias[o];
        float4 r;
        r.x = (acc[oi][0] + cn0 * bv) * iv0;
        r.y = (acc[oi][1] + cn1 * bv) * iv1;
        r.z = (acc[oi][2] + cn2 * bv) * iv2;
        r.w = (acc[oi][3] + cn3 * bv) * iv3;
        *(float4*)(out + ((size_t)b * 128 + o) * NN + n0 + tn * 4) = r;
    }
}

// ---------------------------------------------------------------------------
// K6: out[b][127][n] = deg[n]
// ---------------------------------------------------------------------------
__global__ __launch_bounds__(256) void k_ch127(const int* __restrict__ deg,
                                               float* __restrict__ out) {
    const int t = blockIdx.x * 256 + threadIdx.x;   // < BATCH*NN
    const int b = t >> 12;
    const int n = t & (NN - 1);
    out[((size_t)b * 128 + CCONV) * NN + n] = (float)deg[n];
}

// ---------------------------------------------------------------------------
extern "C" void kernel_launch(void* const* d_in, const int* in_sizes, int n_in,
                              void* d_out, int out_size, void* d_ws, size_t ws_size,
                              hipStream_t stream) {
    const float* x    = (const float*)d_in[0];
    const float* W    = (const float*)d_in[1];
    const float* bias = (const float*)d_in[2];
    const int* idx_i  = (const int*)d_in[3];
    const int* idx_j  = (const int*)d_in[4];
    float* out = (float*)d_out;

    // Workspace layout (bytes) — elist (ushort, 256 KB) and WT (float, 128 KB)
    // share region S: elist's last use (k_agg_csr) precedes k_wt's write
    // (stream-ordered), so the overlap is safe.
    //   xT     : 0          .. 8388608
    //   agg    : 8388608    .. 16777216
    //   S      : 16777216   .. 17039360   (elist ushort[131072] / WT float[32768])
    //   cnt    : 17039360   (+16384)
    //   deg    : 17055744   (+16384)
    //   cursor : 17072128   (+16384)
    //   start  : 17088512   (+16384)  -> end 17104896
    char* ws = (char*)d_ws;
    float*          xT     = (float*)(ws);
    float*          agg    = (float*)(ws + 8388608);
    unsigned short* elist  = (unsigned short*)(ws + 16777216);
    float*          WT     = (float*)(ws + 16777216);
    int*            cnt    = (int*)(ws + 17039360);
    int*            deg    = (int*)(ws + 17055744);
    int*            cursor = (int*)(ws + 17072128);
    int*            start  = (int*)(ws + 17088512);

    // Zero cnt + deg + cursor (contiguous 48 KB)
    hipMemsetAsync(cnt, 0, 49152, stream);

    k_tx<<<dim3(NN / 32, CIN / 32, BATCH), dim3(32, 8), 0, stream>>>(x, xT);
    k_count<<<EE / 256, 256, 0, stream>>>(idx_i, idx_j, cnt, deg);
    k_scan<<<1, 1024, 0, stream>>>(cnt, start);
    k_scatter<<<EE / 256, 256, 0, stream>>>(idx_i, idx_j, start, cursor, elist);
    k_agg_csr<<<NN, 256, 0, stream>>>(xT, start, cnt, elist, agg);
    k_wt<<<(256 * 128) / 256, 256, 0, stream>>>(W, WT);   // after k_agg_csr: overlaps elist
    k_final<<<dim3(NN / 64, BATCH), 256, 0, stream>>>(x, WT, bias, agg, cnt, deg, out);
    k_ch127<<<(BATCH * NN) / 256, 256, 0, stream>>>(deg, out);
}

// Round 3
// 141.144 us; speedup vs baseline: 7.0957x; 1.2247x over previous
//
#include <hip/hip_runtime.h>
#include <cstdint>
#include <cstddef>

// Problem constants (PairwiseConv_22488448761917)
#define BATCH   4
#define CIN     128
#define NN      4096
#define EE      131072
#define CCONV   127      // C_OUT - 1

typedef __attribute__((ext_vector_type(8))) short short8;   // 8 bf16 (4 VGPRs)
typedef __attribute__((ext_vector_type(4))) float f32x4;    // MFMA C/D frag

__device__ __forceinline__ unsigned short f2bf(float f) {
    // round-to-nearest-even fp32 -> bf16
    unsigned int u = __float_as_uint(f);
    return (unsigned short)((u + 0x7FFFu + ((u >> 16) & 1u)) >> 16);
}

// ---------------------------------------------------------------------------
// K1: transpose x (B, C, N) -> xT (B, N, C), tiled 32x32 via LDS
// ---------------------------------------------------------------------------
__global__ __launch_bounds__(256) void k_tx(const float* __restrict__ x,
                                            float* __restrict__ xT) {
    __shared__ float tile[32][33];
    const int b  = blockIdx.z;
    const int n0 = blockIdx.x * 32;
    const int c0 = blockIdx.y * 32;
    const int tx = threadIdx.x;   // 0..31
    const int ty = threadIdx.y;   // 0..7
    const float* xb = x + (size_t)b * CIN * NN;
#pragma unroll
    for (int i = 0; i < 4; ++i)
        tile[ty + i * 8][tx] = xb[(size_t)(c0 + ty + i * 8) * NN + n0 + tx];
    __syncthreads();
    float* xTb = xT + (size_t)b * NN * CIN;
#pragma unroll
    for (int i = 0; i < 4; ++i)
        xTb[(size_t)(n0 + ty + i * 8) * CIN + c0 + tx] = tile[tx][ty + i * 8];
}

// ---------------------------------------------------------------------------
// K2: WTb[o][k] = bf16(WT[k][o]); k<128 -> W[o][k][0], k>=128 -> W[o][k-128][1]
//     row o=127 zero (padding channel).
// ---------------------------------------------------------------------------
__global__ __launch_bounds__(256) void k_wtb(const float* __restrict__ W,
                                             unsigned short* __restrict__ WTb) {
    const int t = blockIdx.x * 256 + threadIdx.x;  // < 128*256
    const int o = t >> 8;
    const int k = t & 255;
    float v = 0.0f;
    if (o < CCONV) {
        const int c = k & 127;
        const int which = k >> 7;
        v = W[((size_t)o * CIN + c) * 2 + which];
    }
    WTb[t] = f2bf(v);
}

// ---------------------------------------------------------------------------
// K3: degree counts. cnt_i from idx_i (scatter target), deg from idx_j.
// ---------------------------------------------------------------------------
__global__ __launch_bounds__(256) void k_count(const int* __restrict__ idx_i,
                                               const int* __restrict__ idx_j,
                                               int* __restrict__ cnt_i,
                                               int* __restrict__ deg) {
    const int e = blockIdx.x * 256 + threadIdx.x;
    atomicAdd(&cnt_i[idx_i[e]], 1);
    atomicAdd(&deg[idx_j[e]], 1);
}

// ---------------------------------------------------------------------------
// K3b: exclusive prefix scan of cnt[4096] -> start[4096].
//      1024 threads x int4; shfl wave scan + 16-wave LDS combine (2 barriers).
// ---------------------------------------------------------------------------
__global__ __launch_bounds__(1024) void k_scan(const int* __restrict__ cnt,
                                               int* __restrict__ start) {
    __shared__ int wsum[16];
    const int tid = threadIdx.x;
    const int4 v = ((const int4*)cnt)[tid];
    const int s = v.x + v.y + v.z + v.w;
    int incl = s;
#pragma unroll
    for (int off = 1; off < 64; off <<= 1) {
        const int t = __shfl_up(incl, off, 64);
        if ((tid & 63) >= off) incl += t;
    }
    if ((tid & 63) == 63) wsum[tid >> 6] = incl;
    __syncthreads();
    if (tid < 16) {
        const int w = wsum[tid];
        int wincl = w;
#pragma unroll
        for (int off = 1; off < 16; off <<= 1) {
            const int t = __shfl_up(wincl, off, 16);
            if (tid >= off) wincl += t;
        }
        wsum[tid] = wincl - w;   // exclusive wave base
    }
    __syncthreads();
    int base = wsum[tid >> 6] + (incl - s);
    int4 o;
    o.x = base;
    o.y = base + v.x;
    o.z = o.y + v.y;
    o.w = o.z + v.z;
    ((int4*)start)[tid] = o;
}

// ---------------------------------------------------------------------------
// K3c: scatter edges into CSR lists: elist[start[ni] + pos] = nj (ushort).
// ---------------------------------------------------------------------------
__global__ __launch_bounds__(256) void k_scatter(const int* __restrict__ idx_i,
                                                 const int* __restrict__ idx_j,
                                                 const int* __restrict__ start,
                                                 int* __restrict__ cursor,
                                                 unsigned short* __restrict__ elist) {
    const int e = blockIdx.x * 256 + threadIdx.x;
    const int ni = idx_i[e];
    const int pos = atomicAdd(&cursor[ni], 1);
    elist[start[ni] + pos] = (unsigned short)idx_j[e];
}

// ---------------------------------------------------------------------------
// K4: CSR aggregation (no float atomics), float4 gathers.
//     Block = 2 nodes x 4 batches x 32 lanes (float4 over 128 channels).
// ---------------------------------------------------------------------------
__global__ __launch_bounds__(256) void k_agg_csr(const float* __restrict__ xT,
                                                 const int* __restrict__ start,
                                                 const int* __restrict__ cnt,
                                                 const unsigned short* __restrict__ elist,
                                                 float* __restrict__ agg) {
    const int tid = threadIdx.x;
    const int n   = blockIdx.x * 2 + (tid >> 7);
    const int b   = (tid >> 5) & 3;
    const int c4  = (tid & 31) << 2;
    const int s0  = start[n];
    const int dn  = cnt[n];
    const float* xb = xT + (size_t)b * NN * CIN + c4;
    float4 acc = {0.0f, 0.0f, 0.0f, 0.0f};
    int k = 0;
    for (; k + 2 <= dn; k += 2) {
        const int nj0 = elist[s0 + k];
        const int nj1 = elist[s0 + k + 1];
        const float4 v0 = *(const float4*)(xb + (size_t)nj0 * CIN);
        const float4 v1 = *(const float4*)(xb + (size_t)nj1 * CIN);
        acc.x += v0.x + v1.x;
        acc.y += v0.y + v1.y;
        acc.z += v0.z + v1.z;
        acc.w += v0.w + v1.w;
    }
    if (k < dn) {
        const int nj = elist[s0 + k];
        const float4 v = *(const float4*)(xb + (size_t)nj * CIN);
        acc.x += v.x; acc.y += v.y; acc.z += v.z; acc.w += v.w;
    }
    *(float4*)(agg + ((size_t)b * NN + n) * CIN + c4) = acc;
}

// ---------------------------------------------------------------------------
// K5: final GEMM via bf16 MFMA 16x16x32 + fused epilogue + ch127 row.
//   Out tile per block: 64 cols (j = n0..n0+63) x 128 rows (o), K = 256.
//   A (M=j, K) = Z^T staged in LDS pre-packed in MFMA A-frag order:
//     unit u = (mt*8 + kt)*64 + lane, holding Z[j=mt*16+(lane&15)]
//     [k = kt*32 + (lane>>4)*8 .. +8) as 8 bf16 (16 B). Wave-contiguous
//     ds_write_b128 / ds_read_b128 -> conflict-free by construction.
//   B (K, N=o) read from global WTb[o][k] (64 KB, L2-hot).
//   D layout (m89): col=lane&15 (o-within-tile), row=(lane>>4)*4+reg (j).
// ---------------------------------------------------------------------------
__global__ __launch_bounds__(256) void k_final(const float* __restrict__ xT,
                                               const unsigned short* __restrict__ WTb,
                                               const float* __restrict__ bias,
                                               const float* __restrict__ agg,
                                               const int* __restrict__ cnt_i,
                                               const int* __restrict__ deg,
                                               float* __restrict__ out) {
    __shared__ short Af[2048 * 8];          // 32 KB, A-frag order
    __shared__ float cntf[64], invd[64], degf[64], biasf[128];

    const int tid = threadIdx.x;
    const int b   = blockIdx.y;
    const int n0  = blockIdx.x * 64;

    if (tid < 64) {
        const int c = cnt_i[n0 + tid];
        const int d = deg[n0 + tid];
        cntf[tid] = (float)c;
        degf[tid] = (float)d;
        invd[tid] = (d == 0) ? 1.0f : 1.0f / (float)d;
    } else if (tid < 192) {
        const int o = tid - 64;
        biasf[o] = (o < CCONV) ? bias[o] : 0.0f;
    }
    __syncthreads();

    // Stage A fragments: 2048 units / 256 threads = 8 iterations.
    for (int u = tid; u < 2048; u += 256) {
        const int L  = u & 63;
        const int kt = (u >> 6) & 7;
        const int mt = u >> 9;
        const int j  = mt * 16 + (L & 15);
        const int k0 = kt * 32 + (L >> 4) * 8;
        const float* src;
        float sc;
        if (k0 < 128) {
            src = xT + ((size_t)b * NN + n0 + j) * CIN + k0;
            sc  = cntf[j];
        } else {
            src = agg + ((size_t)b * NN + n0 + j) * CIN + (k0 - 128);
            sc  = 1.0f;
        }
        const float4 v0 = *(const float4*)src;
        const float4 v1 = *(const float4*)(src + 4);
        short8 p;
        p[0] = (short)f2bf(v0.x * sc);
        p[1] = (short)f2bf(v0.y * sc);
        p[2] = (short)f2bf(v0.z * sc);
        p[3] = (short)f2bf(v0.w * sc);
        p[4] = (short)f2bf(v1.x * sc);
        p[5] = (short)f2bf(v1.y * sc);
        p[6] = (short)f2bf(v1.z * sc);
        p[7] = (short)f2bf(v1.w * sc);
        *(short8*)&Af[u * 8] = p;
    }
    __syncthreads();

    const int lane = tid & 63;
    const int w    = tid >> 6;      // wave id: o-range [w*32, w*32+32)
    const int m    = lane & 15;
    const int g    = lane >> 4;

    f32x4 acc[4][2];
#pragma unroll
    for (int mt = 0; mt < 4; ++mt)
#pragma unroll
        for (int nt = 0; nt < 2; ++nt)
            acc[mt][nt] = (f32x4){0.0f, 0.0f, 0.0f, 0.0f};

    const unsigned short* B0 = WTb + ((size_t)(w * 32 + m)) * 256;
    const unsigned short* B1 = B0 + 16 * 256;

#pragma unroll
    for (int kt = 0; kt < 8; ++kt) {
        const int k0 = kt * 32 + g * 8;
        const short8 b0 = *(const short8*)(B0 + k0);
        const short8 b1 = *(const short8*)(B1 + k0);
        const short8 a0 = *(const short8*)&Af[((0 * 8 + kt) * 64 + lane) * 8];
        const short8 a1 = *(const short8*)&Af[((1 * 8 + kt) * 64 + lane) * 8];
        const short8 a2 = *(const short8*)&Af[((2 * 8 + kt) * 64 + lane) * 8];
        const short8 a3 = *(const short8*)&Af[((3 * 8 + kt) * 64 + lane) * 8];
        acc[0][0] = __builtin_amdgcn_mfma_f32_16x16x32_bf16(a0, b0, acc[0][0], 0, 0, 0);
        acc[0][1] = __builtin_amdgcn_mfma_f32_16x16x32_bf16(a0, b1, acc[0][1], 0, 0, 0);
        acc[1][0] = __builtin_amdgcn_mfma_f32_16x16x32_bf16(a1, b0, acc[1][0], 0, 0, 0);
        acc[1][1] = __builtin_amdgcn_mfma_f32_16x16x32_bf16(a1, b1, acc[1][1], 0, 0, 0);
        acc[2][0] = __builtin_amdgcn_mfma_f32_16x16x32_bf16(a2, b0, acc[2][0], 0, 0, 0);
        acc[2][1] = __builtin_amdgcn_mfma_f32_16x16x32_bf16(a2, b1, acc[2][1], 0, 0, 0);
        acc[3][0] = __builtin_amdgcn_mfma_f32_16x16x32_bf16(a3, b0, acc[3][0], 0, 0, 0);
        acc[3][1] = __builtin_amdgcn_mfma_f32_16x16x32_bf16(a3, b1, acc[3][1], 0, 0, 0);
    }

    // Epilogue: D[row=j][col=o]; 4 regs = 4 consecutive j at fixed o.
#pragma unroll
    for (int nt = 0; nt < 2; ++nt) {
        const int o = w * 32 + nt * 16 + m;
        if (o >= CCONV) continue;   // o==127 handled below with deg row
        const float bo = biasf[o];
        float* orow = out + ((size_t)b * 128 + o) * NN + n0;
#pragma unroll
        for (int mt = 0; mt < 4; ++mt) {
            const int j0 = mt * 16 + g * 4;
            float4 r;
            r.x = (acc[mt][nt][0] + cntf[j0 + 0] * bo) * invd[j0 + 0];
            r.y = (acc[mt][nt][1] + cntf[j0 + 1] * bo) * invd[j0 + 1];
            r.z = (acc[mt][nt][2] + cntf[j0 + 2] * bo) * invd[j0 + 2];
            r.w = (acc[mt][nt][3] + cntf[j0 + 3] * bo) * invd[j0 + 3];
            *(float4*)(orow + j0) = r;
        }
    }
    // fused ch127: out[b][127][n] = deg[n]
    if (tid < 64)
        out[((size_t)b * 128 + CCONV) * NN + n0 + tid] = degf[tid];
}

// ---------------------------------------------------------------------------
extern "C" void kernel_launch(void* const* d_in, const int* in_sizes, int n_in,
                              void* d_out, int out_size, void* d_ws, size_t ws_size,
                              hipStream_t stream) {
    const float* x    = (const float*)d_in[0];
    const float* W    = (const float*)d_in[1];
    const float* bias = (const float*)d_in[2];
    const int* idx_i  = (const int*)d_in[3];
    const int* idx_j  = (const int*)d_in[4];
    float* out = (float*)d_out;

    // Workspace layout (bytes):
    //   xT     : 0          (+8388608)
    //   agg    : 8388608    (+8388608)
    //   elist  : 16777216   (+262144)   ushort[E]
    //   WTb    : 17039360   (+65536)    bf16[128][256]
    //   cnt    : 17104896   (+16384)
    //   deg    : 17121280   (+16384)
    //   cursor : 17137664   (+16384)
    //   start  : 17154048   (+16384)    -> end 17170432 (~16.4 MB)
    char* ws = (char*)d_ws;
    float*          xT     = (float*)(ws);
    float*          agg    = (float*)(ws + 8388608);
    unsigned short* elist  = (unsigned short*)(ws + 16777216);
    unsigned short* WTb    = (unsigned short*)(ws + 17039360);
    int*            cnt    = (int*)(ws + 17104896);
    int*            deg    = (int*)(ws + 17121280);
    int*            cursor = (int*)(ws + 17137664);
    int*            start  = (int*)(ws + 17154048);

    // Zero cnt + deg + cursor (contiguous 48 KB)
    hipMemsetAsync(cnt, 0, 49152, stream);

    k_tx<<<dim3(NN / 32, CIN / 32, BATCH), dim3(32, 8), 0, stream>>>(x, xT);
    k_wtb<<<(128 * 256) / 256, 256, 0, stream>>>(W, WTb);
    k_count<<<EE / 256, 256, 0, stream>>>(idx_i, idx_j, cnt, deg);
    k_scan<<<1, 1024, 0, stream>>>(cnt, start);
    k_scatter<<<EE / 256, 256, 0, stream>>>(idx_i, idx_j, start, cursor, elist);
    k_agg_csr<<<NN / 2, 256, 0, stream>>>(xT, start, cnt, elist, agg);
    k_final<<<dim3(NN / 64, BATCH), 256, 0, stream>>>(xT, WTb, bias, agg, cnt, deg, out);
}

// Round 4
// 125.843 us; speedup vs baseline: 7.9585x; 1.1216x over previous
//
#include <hip/hip_runtime.h>
#include <cstdint>
#include <cstddef>

// Problem constants (PairwiseConv_22488448761917)
#define BATCH   4
#define CIN     128
#define NN      4096
#define EE      131072
#define CCONV   127      // C_OUT - 1
#define NBC     512      // B*C elements per node row in (N,B,C) layout

typedef __attribute__((ext_vector_type(8))) short short8;   // 8 bf16 (4 VGPRs)
typedef __attribute__((ext_vector_type(4))) float f32x4;    // MFMA C/D frag

__device__ __forceinline__ unsigned short f2bf(float f) {
    unsigned int u = __float_as_uint(f);
    return (unsigned short)((u + 0x7FFFu + ((u >> 16) & 1u)) >> 16);
}
__device__ __forceinline__ float bf2f(unsigned short h) {
    return __uint_as_float((unsigned int)h << 16);
}

// ---------------------------------------------------------------------------
// K_pre (fused): blocks [0,2048)  : transpose x (B,C,N) fp32 -> xT (N,B,C) bf16
//                blocks [2048,2560): degree counts (cnt_i from idx_i, deg from idx_j)
//                blocks [2560,2688): WTb[o][k] bf16 weight repack
// ---------------------------------------------------------------------------
__global__ __launch_bounds__(256) void k_pre(const float* __restrict__ x,
                                             unsigned short* __restrict__ xT,
                                             const float* __restrict__ W,
                                             unsigned short* __restrict__ WTb,
                                             const int* __restrict__ idx_i,
                                             const int* __restrict__ idx_j,
                                             int* __restrict__ cnt_i,
                                             int* __restrict__ deg) {
    const int bid = blockIdx.x;
    const int tid = threadIdx.x;
    if (bid < 2048) {
        __shared__ float tile[32][33];
        const int nb = bid & 127;
        const int cb = (bid >> 7) & 3;
        const int b  = bid >> 9;
        const int n0 = nb * 32, c0 = cb * 32;
        const int tx = tid & 31, ty = tid >> 5;   // 32 x 8
        const float* xb = x + (size_t)b * CIN * NN;
#pragma unroll
        for (int i = 0; i < 4; ++i)
            tile[ty + i * 8][tx] = xb[(size_t)(c0 + ty + i * 8) * NN + n0 + tx];
        __syncthreads();
#pragma unroll
        for (int i = 0; i < 4; ++i) {
            const int nl = ty + i * 8;
            xT[(size_t)(n0 + nl) * NBC + b * CIN + c0 + tx] = f2bf(tile[tx][nl]);
        }
    } else if (bid < 2560) {
        const int e = (bid - 2048) * 256 + tid;
        atomicAdd(&cnt_i[idx_i[e]], 1);
        atomicAdd(&deg[idx_j[e]], 1);
    } else {
        const int t = (bid - 2560) * 256 + tid;   // < 128*256
        const int o = t >> 8;
        const int k = t & 255;
        float v = 0.0f;
        if (o < CCONV) v = W[((size_t)o * CIN + (k & 127)) * 2 + (k >> 7)];
        WTb[t] = f2bf(v);
    }
}

// ---------------------------------------------------------------------------
// K_scan: exclusive prefix scan of cnt[4096] -> start[4096].
//         1024 threads x int4; shfl wave scan + 16-wave LDS combine.
// ---------------------------------------------------------------------------
__global__ __launch_bounds__(1024) void k_scan(const int* __restrict__ cnt,
                                               int* __restrict__ start) {
    __shared__ int wsum[16];
    const int tid = threadIdx.x;
    const int4 v = ((const int4*)cnt)[tid];
    const int s = v.x + v.y + v.z + v.w;
    int incl = s;
#pragma unroll
    for (int off = 1; off < 64; off <<= 1) {
        const int t = __shfl_up(incl, off, 64);
        if ((tid & 63) >= off) incl += t;
    }
    if ((tid & 63) == 63) wsum[tid >> 6] = incl;
    __syncthreads();
    if (tid < 16) {
        const int w = wsum[tid];
        int wincl = w;
#pragma unroll
        for (int off = 1; off < 16; off <<= 1) {
            const int t = __shfl_up(wincl, off, 16);
            if (tid >= off) wincl += t;
        }
        wsum[tid] = wincl - w;
    }
    __syncthreads();
    int base = wsum[tid >> 6] + (incl - s);
    int4 o;
    o.x = base;
    o.y = base + v.x;
    o.z = o.y + v.y;
    o.w = o.z + v.z;
    ((int4*)start)[tid] = o;
}

// ---------------------------------------------------------------------------
// K_scatter: CSR edge lists: elist[start[ni] + pos] = nj (ushort).
// ---------------------------------------------------------------------------
__global__ __launch_bounds__(256) void k_scatter(const int* __restrict__ idx_i,
                                                 const int* __restrict__ idx_j,
                                                 const int* __restrict__ start,
                                                 int* __restrict__ cursor,
                                                 unsigned short* __restrict__ elist) {
    const int e = blockIdx.x * 256 + threadIdx.x;
    const int ni = idx_i[e];
    const int pos = atomicAdd(&cursor[ni], 1);
    elist[start[ni] + pos] = (unsigned short)idx_j[e];
}

// ---------------------------------------------------------------------------
// K_agg: CSR aggregation, bf16 in / fp32 accumulate / bf16 out.
//   (N,B,C) layout: each edge gathers one contiguous 1 KB block
//   (128 lanes x 8 B). Block = 2 nodes x 128 lanes.
// ---------------------------------------------------------------------------
__global__ __launch_bounds__(256) void k_agg(const unsigned short* __restrict__ xT,
                                             const int* __restrict__ start,
                                             const int* __restrict__ cnt,
                                             const unsigned short* __restrict__ elist,
                                             unsigned short* __restrict__ agg) {
    const int tid = threadIdx.x;
    const int n   = blockIdx.x * 2 + (tid >> 7);
    const int off = (tid & 127) * 4;    // element offset within 512-elem node row
    const int s0  = start[n];
    const int dn  = cnt[n];
    float4 acc = {0.0f, 0.0f, 0.0f, 0.0f};
    int k = 0;
    for (; k + 2 <= dn; k += 2) {
        const int nj0 = elist[s0 + k];
        const int nj1 = elist[s0 + k + 1];
        const ushort4 u0 = *(const ushort4*)(xT + (size_t)nj0 * NBC + off);
        const ushort4 u1 = *(const ushort4*)(xT + (size_t)nj1 * NBC + off);
        acc.x += bf2f(u0.x) + bf2f(u1.x);
        acc.y += bf2f(u0.y) + bf2f(u1.y);
        acc.z += bf2f(u0.z) + bf2f(u1.z);
        acc.w += bf2f(u0.w) + bf2f(u1.w);
    }
    if (k < dn) {
        const int nj = elist[s0 + k];
        const ushort4 u = *(const ushort4*)(xT + (size_t)nj * NBC + off);
        acc.x += bf2f(u.x);
        acc.y += bf2f(u.y);
        acc.z += bf2f(u.z);
        acc.w += bf2f(u.w);
    }
    ushort4 r;
    r.x = f2bf(acc.x);
    r.y = f2bf(acc.y);
    r.z = f2bf(acc.z);
    r.w = f2bf(acc.w);
    *(ushort4*)(agg + (size_t)n * NBC + off) = r;
}

// ---------------------------------------------------------------------------
// K_final: bf16 MFMA 16x16x32 GEMM + fused epilogue + ch127 row.
//   Out tile per block: 64 cols (j) x 128 rows (o), K = 256.
//   A staged in LDS pre-packed in MFMA A-frag order (unit = 16 B, wave-
//   contiguous ds_write_b128/ds_read_b128 -> conflict-free).
//   B read from global WTb[o][k] (64 KB, L2-hot).
//   D layout: col(o)=lane&15, row(j)=(lane>>4)*4+reg.
// ---------------------------------------------------------------------------
__global__ __launch_bounds__(256) void k_final(const unsigned short* __restrict__ xT,
                                               const unsigned short* __restrict__ WTb,
                                               const float* __restrict__ bias,
                                               const unsigned short* __restrict__ agg,
                                               const int* __restrict__ cnt_i,
                                               const int* __restrict__ deg,
                                               float* __restrict__ out) {
    __shared__ short Af[2048 * 8];          // 32 KB, A-frag order
    __shared__ float cntf[64], invd[64], degf[64], biasf[128];

    const int tid = threadIdx.x;
    const int b   = blockIdx.y;
    const int n0  = blockIdx.x * 64;

    if (tid < 64) {
        const int c = cnt_i[n0 + tid];
        const int d = deg[n0 + tid];
        cntf[tid] = (float)c;
        degf[tid] = (float)d;
        invd[tid] = (d == 0) ? 1.0f : 1.0f / (float)d;
    } else if (tid < 192) {
        const int o = tid - 64;
        biasf[o] = (o < CCONV) ? bias[o] : 0.0f;
    }
    __syncthreads();

    // Stage A fragments: 2048 units (16 B each) / 256 threads = 8 iters.
    for (int u = tid; u < 2048; u += 256) {
        const int L  = u & 63;
        const int kt = (u >> 6) & 7;
        const int mt = u >> 9;
        const int j  = mt * 16 + (L & 15);
        const int k0 = kt * 32 + (L >> 4) * 8;
        short8 p;
        if (k0 < 128) {
            const short8 a = *(const short8*)(xT + (size_t)(n0 + j) * NBC + b * CIN + k0);
            const float sc = cntf[j];
#pragma unroll
            for (int q = 0; q < 8; ++q)
                p[q] = (short)f2bf(bf2f((unsigned short)a[q]) * sc);
        } else {
            p = *(const short8*)(agg + (size_t)(n0 + j) * NBC + b * CIN + (k0 - 128));
        }
        *(short8*)&Af[u * 8] = p;
    }
    __syncthreads();

    const int lane = tid & 63;
    const int w    = tid >> 6;      // wave id: o-range [w*32, w*32+32)
    const int m    = lane & 15;
    const int g    = lane >> 4;

    f32x4 acc[4][2];
#pragma unroll
    for (int mt = 0; mt < 4; ++mt)
#pragma unroll
        for (int nt = 0; nt < 2; ++nt)
            acc[mt][nt] = (f32x4){0.0f, 0.0f, 0.0f, 0.0f};

    const unsigned short* B0 = WTb + ((size_t)(w * 32 + m)) * 256;
    const unsigned short* B1 = B0 + 16 * 256;

#pragma unroll
    for (int kt = 0; kt < 8; ++kt) {
        const int k0 = kt * 32 + g * 8;
        const short8 b0 = *(const short8*)(B0 + k0);
        const short8 b1 = *(const short8*)(B1 + k0);
        const short8 a0 = *(const short8*)&Af[((0 * 8 + kt) * 64 + lane) * 8];
        const short8 a1 = *(const short8*)&Af[((1 * 8 + kt) * 64 + lane) * 8];
        const short8 a2 = *(const short8*)&Af[((2 * 8 + kt) * 64 + lane) * 8];
        const short8 a3 = *(const short8*)&Af[((3 * 8 + kt) * 64 + lane) * 8];
        acc[0][0] = __builtin_amdgcn_mfma_f32_16x16x32_bf16(a0, b0, acc[0][0], 0, 0, 0);
        acc[0][1] = __builtin_amdgcn_mfma_f32_16x16x32_bf16(a0, b1, acc[0][1], 0, 0, 0);
        acc[1][0] = __builtin_amdgcn_mfma_f32_16x16x32_bf16(a1, b0, acc[1][0], 0, 0, 0);
        acc[1][1] = __builtin_amdgcn_mfma_f32_16x16x32_bf16(a1, b1, acc[1][1], 0, 0, 0);
        acc[2][0] = __builtin_amdgcn_mfma_f32_16x16x32_bf16(a2, b0, acc[2][0], 0, 0, 0);
        acc[2][1] = __builtin_amdgcn_mfma_f32_16x16x32_bf16(a2, b1, acc[2][1], 0, 0, 0);
        acc[3][0] = __builtin_amdgcn_mfma_f32_16x16x32_bf16(a3, b0, acc[3][0], 0, 0, 0);
        acc[3][1] = __builtin_amdgcn_mfma_f32_16x16x32_bf16(a3, b1, acc[3][1], 0, 0, 0);
    }

    // Epilogue: D[row=j][col=o]; 4 regs = 4 consecutive j at fixed o.
#pragma unroll
    for (int nt = 0; nt < 2; ++nt) {
        const int o = w * 32 + nt * 16 + m;
        if (o >= CCONV) continue;   // o==127 handled below
        const float bo = biasf[o];
        float* orow = out + ((size_t)b * 128 + o) * NN + n0;
#pragma unroll
        for (int mt = 0; mt < 4; ++mt) {
            const int j0 = mt * 16 + g * 4;
            float4 r;
            r.x = (acc[mt][nt][0] + cntf[j0 + 0] * bo) * invd[j0 + 0];
            r.y = (acc[mt][nt][1] + cntf[j0 + 1] * bo) * invd[j0 + 1];
            r.z = (acc[mt][nt][2] + cntf[j0 + 2] * bo) * invd[j0 + 2];
            r.w = (acc[mt][nt][3] + cntf[j0 + 3] * bo) * invd[j0 + 3];
            *(float4*)(orow + j0) = r;
        }
    }
    // fused ch127: out[b][127][n] = deg[n]
    if (tid < 64)
        out[((size_t)b * 128 + CCONV) * NN + n0 + tid] = degf[tid];
}

// ---------------------------------------------------------------------------
extern "C" void kernel_launch(void* const* d_in, const int* in_sizes, int n_in,
                              void* d_out, int out_size, void* d_ws, size_t ws_size,
                              hipStream_t stream) {
    const float* x    = (const float*)d_in[0];
    const float* W    = (const float*)d_in[1];
    const float* bias = (const float*)d_in[2];
    const int* idx_i  = (const int*)d_in[3];
    const int* idx_j  = (const int*)d_in[4];
    float* out = (float*)d_out;

    // Workspace layout (bytes):
    //   xT     : 0        (+4194304)   bf16 (N,B,C)
    //   agg    : 4194304  (+4194304)   bf16 (N,B,C)
    //   elist  : 8388608  (+262144)    ushort[E]
    //   WTb    : 8650752  (+65536)     bf16[128][256]
    //   cnt    : 8716288  (+16384)
    //   deg    : 8732672  (+16384)
    //   cursor : 8749056  (+16384)
    //   start  : 8765440  (+16384)     -> end 8781824 (~8.4 MB)
    char* ws = (char*)d_ws;
    unsigned short* xT     = (unsigned short*)(ws);
    unsigned short* agg    = (unsigned short*)(ws + 4194304);
    unsigned short* elist  = (unsigned short*)(ws + 8388608);
    unsigned short* WTb    = (unsigned short*)(ws + 8650752);
    int*            cnt    = (int*)(ws + 8716288);
    int*            deg    = (int*)(ws + 8732672);
    int*            cursor = (int*)(ws + 8749056);
    int*            start  = (int*)(ws + 8765440);

    // Zero cnt + deg + cursor (contiguous 48 KB)
    hipMemsetAsync(cnt, 0, 49152, stream);

    k_pre<<<2688, 256, 0, stream>>>(x, xT, W, WTb, idx_i, idx_j, cnt, deg);
    k_scan<<<1, 1024, 0, stream>>>(cnt, start);
    k_scatter<<<EE / 256, 256, 0, stream>>>(idx_i, idx_j, start, cursor, elist);
    k_agg<<<NN / 2, 256, 0, stream>>>(xT, start, cnt, elist, agg);
    k_final<<<dim3(NN / 64, BATCH), 256, 0, stream>>>(xT, WTb, bias, agg, cnt, deg, out);
}

// Round 5
// 118.323 us; speedup vs baseline: 8.4643x; 1.0636x over previous
//
#include <hip/hip_runtime.h>
#include <cstdint>
#include <cstddef>

// Problem constants (PairwiseConv_22488448761917)
#define BATCH   4
#define CIN     128
#define NN      4096
#define EE      131072
#define CCONV   127      // C_OUT - 1
#define NBC     512      // B*C elements per node row in (N,B,C) layout
#define MAXDEG  128      // ELL row capacity; deg ~ Bin(131072,1/4096), P(>128) ~ e^-81

typedef __attribute__((ext_vector_type(8))) short short8;            // 8 bf16
typedef __attribute__((ext_vector_type(8))) unsigned short ushort8;  // 8 bf16 bits
typedef __attribute__((ext_vector_type(4))) float f32x4;             // MFMA C/D frag

__device__ __forceinline__ unsigned short f2bf(float f) {
    unsigned int u = __float_as_uint(f);
    return (unsigned short)((u + 0x7FFFu + ((u >> 16) & 1u)) >> 16);
}
__device__ __forceinline__ float bf2f(unsigned short h) {
    return __uint_as_float((unsigned int)h << 16);
}

// ---------------------------------------------------------------------------
// K1 (fused pre):
//   blocks [0,2048)    : transpose x (B,C,N) fp32 -> xT (N,B,C) bf16
//   blocks [2048,2560) : ELL build: elist[ni*128+pos]=nj (cursor atomics)
//                        + deg[nj]++  (cursor becomes cnt_i when done)
//   blocks [2560,2688) : WTb[o][k] bf16 weight repack
// ---------------------------------------------------------------------------
__global__ __launch_bounds__(256) void k_pre(const float* __restrict__ x,
                                             unsigned short* __restrict__ xT,
                                             const float* __restrict__ W,
                                             unsigned short* __restrict__ WTb,
                                             const int* __restrict__ idx_i,
                                             const int* __restrict__ idx_j,
                                             int* __restrict__ cursor,
                                             unsigned short* __restrict__ elist,
                                             int* __restrict__ deg) {
    const int bid = blockIdx.x;
    const int tid = threadIdx.x;
    if (bid < 2048) {
        __shared__ float tile[32][33];
        const int nb = bid & 127;
        const int cb = (bid >> 7) & 3;
        const int b  = bid >> 9;
        const int n0 = nb * 32, c0 = cb * 32;
        const int tx = tid & 31, ty = tid >> 5;   // 32 x 8
        const float* xb = x + (size_t)b * CIN * NN;
#pragma unroll
        for (int i = 0; i < 4; ++i)
            tile[ty + i * 8][tx] = xb[(size_t)(c0 + ty + i * 8) * NN + n0 + tx];
        __syncthreads();
#pragma unroll
        for (int i = 0; i < 4; ++i) {
            const int nl = ty + i * 8;
            xT[(size_t)(n0 + nl) * NBC + b * CIN + c0 + tx] = f2bf(tile[tx][nl]);
        }
    } else if (bid < 2560) {
        const int e  = (bid - 2048) * 256 + tid;
        const int ni = idx_i[e];
        const int nj = idx_j[e];
        const int pos = atomicAdd(&cursor[ni], 1);
        elist[(size_t)ni * MAXDEG + pos] = (unsigned short)nj;
        atomicAdd(&deg[nj], 1);
    } else {
        const int t = (bid - 2560) * 256 + tid;   // < 128*256
        const int o = t >> 8;
        const int k = t & 255;
        float v = 0.0f;
        if (o < CCONV) v = W[((size_t)o * CIN + (k & 127)) * 2 + (k >> 7)];
        WTb[t] = f2bf(v);
    }
}

// ---------------------------------------------------------------------------
// K2 (final, with inline gather-aggregation):
//   Block = (32-node tile n0..n0+31) x (batch b). 256 threads = 4 waves.
//   Phase A: each wave gathers neighbor rows for its 8 nodes (4 nodes x
//     16 lanes x 8ch ushort8), accumulates fp32, writes bf16 16B units
//     directly into LDS A-frag slots kt=4..7 (the agg half of Z).
//   Phase B: x-part (kt=0..3): Z = xT * cnt, staged in A-frag order.
//   Phase C: MFMA 16x16x32 bf16, M=32 (2 m-tiles) x N=128(o) x K=256.
//     B from global WTb[o][k] (64 KB, L2-hot).
//     D layout (m89): col(o)=lane&15, row(j)=(lane>>4)*4+reg.
//   Phase D: epilogue (cnt*bias, /deg) + ch127 = deg row.
// ---------------------------------------------------------------------------
__global__ __launch_bounds__(256) void k_final(const unsigned short* __restrict__ xT,
                                               const unsigned short* __restrict__ WTb,
                                               const float* __restrict__ bias,
                                               const unsigned short* __restrict__ elist,
                                               const int* __restrict__ cnt_i,
                                               const int* __restrict__ deg,
                                               float* __restrict__ out) {
    __shared__ short Af[1024 * 8];          // 16 KB, A-frag order (2 mt x 8 kt x 64 x 16B)
    __shared__ float cntf[32], invd[32], degf[32], biasf[128];
    __shared__ int   cnti[32];

    const int tid = threadIdx.x;
    const int b   = blockIdx.y;
    const int n0  = blockIdx.x * 32;

    if (tid < 32) {
        const int c = cnt_i[n0 + tid];
        const int d = deg[n0 + tid];
        cnti[tid] = c;
        cntf[tid] = (float)c;
        degf[tid] = (float)d;
        invd[tid] = (d == 0) ? 1.0f : 1.0f / (float)d;
    } else if (tid >= 64 && tid < 192) {
        const int o = tid - 64;
        biasf[o] = (o < CCONV) ? bias[o] : 0.0f;
    }
    __syncthreads();

    const int lane = tid & 63;
    const int w    = tid >> 6;

    // ---- Phase A: inline gather-agg -> A-frag slots kt 4..7 ----
    {
        const int ns = lane >> 4;           // 0..3: node within group of 4
        const int c0 = (lane & 15) * 8;     // channel base (8 ch per lane)
        const unsigned short* xb = xT + b * CIN + c0;
#pragma unroll
        for (int pg = 0; pg < 2; ++pg) {
            const int j  = w * 8 + pg * 4 + ns;
            const int dn = cnti[j];
            const unsigned short* erow = elist + (size_t)(n0 + j) * MAXDEG;
            float acc[8] = {0, 0, 0, 0, 0, 0, 0, 0};
            int k = 0;
            for (; k + 2 <= dn; k += 2) {
                const int nj0 = erow[k];
                const int nj1 = erow[k + 1];
                const ushort8 u0 = *(const ushort8*)(xb + (size_t)nj0 * NBC);
                const ushort8 u1 = *(const ushort8*)(xb + (size_t)nj1 * NBC);
#pragma unroll
                for (int q = 0; q < 8; ++q) acc[q] += bf2f(u0[q]) + bf2f(u1[q]);
            }
            if (k < dn) {
                const int nj = erow[k];
                const ushort8 u = *(const ushort8*)(xb + (size_t)nj * NBC);
#pragma unroll
                for (int q = 0; q < 8; ++q) acc[q] += bf2f(u[q]);
            }
            short8 p;
#pragma unroll
            for (int q = 0; q < 8; ++q) p[q] = (short)f2bf(acc[q]);
            // k = 128 + c0 -> kt = 4 + (c0>>5), g = (c0>>3)&3
            const int kt   = 4 + (c0 >> 5);
            const int g    = (c0 >> 3) & 3;
            const int unit = ((j >> 4) * 8 + kt) * 64 + (j & 15) + 16 * g;
            *(short8*)&Af[unit * 8] = p;
        }
    }

    // ---- Phase B: x-part staging (kt 0..3), 512 units / 256 threads ----
#pragma unroll
    for (int it = 0; it < 2; ++it) {
        const int u  = tid + it * 256;
        const int L  = u & 63;
        const int kt = (u >> 6) & 3;
        const int mt = u >> 8;
        const int j  = mt * 16 + (L & 15);
        const int k0 = kt * 32 + (L >> 4) * 8;
        const short8 a = *(const short8*)(xT + (size_t)(n0 + j) * NBC + b * CIN + k0);
        const float sc = cntf[j];
        short8 p;
#pragma unroll
        for (int q = 0; q < 8; ++q)
            p[q] = (short)f2bf(bf2f((unsigned short)a[q]) * sc);
        *(short8*)&Af[((mt * 8 + kt) * 64 + L) * 8] = p;
    }
    __syncthreads();

    // ---- Phase C: MFMA ----
    const int m = lane & 15;
    const int g = lane >> 4;

    f32x4 acc[2][2];
#pragma unroll
    for (int mt = 0; mt < 2; ++mt)
#pragma unroll
        for (int nt = 0; nt < 2; ++nt)
            acc[mt][nt] = (f32x4){0.0f, 0.0f, 0.0f, 0.0f};

    const unsigned short* B0 = WTb + (size_t)(w * 32 + m) * 256;
    const unsigned short* B1 = B0 + 16 * 256;

#pragma unroll
    for (int kt = 0; kt < 8; ++kt) {
        const int k0 = kt * 32 + g * 8;
        const short8 b0 = *(const short8*)(B0 + k0);
        const short8 b1 = *(const short8*)(B1 + k0);
        const short8 a0 = *(const short8*)&Af[((0 * 8 + kt) * 64 + lane) * 8];
        const short8 a1 = *(const short8*)&Af[((1 * 8 + kt) * 64 + lane) * 8];
        acc[0][0] = __builtin_amdgcn_mfma_f32_16x16x32_bf16(a0, b0, acc[0][0], 0, 0, 0);
        acc[0][1] = __builtin_amdgcn_mfma_f32_16x16x32_bf16(a0, b1, acc[0][1], 0, 0, 0);
        acc[1][0] = __builtin_amdgcn_mfma_f32_16x16x32_bf16(a1, b0, acc[1][0], 0, 0, 0);
        acc[1][1] = __builtin_amdgcn_mfma_f32_16x16x32_bf16(a1, b1, acc[1][1], 0, 0, 0);
    }

    // ---- Phase D: epilogue ----
#pragma unroll
    for (int nt = 0; nt < 2; ++nt) {
        const int o = w * 32 + nt * 16 + m;
        if (o >= CCONV) continue;   // o==127 handled below
        const float bo = biasf[o];
        float* orow = out + ((size_t)b * 128 + o) * NN + n0;
#pragma unroll
        for (int mt = 0; mt < 2; ++mt) {
            const int j0 = mt * 16 + g * 4;
            float4 r;
            r.x = (acc[mt][nt][0] + cntf[j0 + 0] * bo) * invd[j0 + 0];
            r.y = (acc[mt][nt][1] + cntf[j0 + 1] * bo) * invd[j0 + 1];
            r.z = (acc[mt][nt][2] + cntf[j0 + 2] * bo) * invd[j0 + 2];
            r.w = (acc[mt][nt][3] + cntf[j0 + 3] * bo) * invd[j0 + 3];
            *(float4*)(orow + j0) = r;
        }
    }
    // fused ch127: out[b][127][n] = deg[n]
    if (tid < 32)
        out[((size_t)b * 128 + CCONV) * NN + n0 + tid] = degf[tid];
}

// ---------------------------------------------------------------------------
extern "C" void kernel_launch(void* const* d_in, const int* in_sizes, int n_in,
                              void* d_out, int out_size, void* d_ws, size_t ws_size,
                              hipStream_t stream) {
    const float* x    = (const float*)d_in[0];
    const float* W    = (const float*)d_in[1];
    const float* bias = (const float*)d_in[2];
    const int* idx_i  = (const int*)d_in[3];
    const int* idx_j  = (const int*)d_in[4];
    float* out = (float*)d_out;

    // Workspace layout (bytes):
    //   xT     : 0        (+4194304)   bf16 (N,B,C)
    //   elist  : 4194304  (+1048576)   ushort[N][128] ELL
    //   WTb    : 5242880  (+65536)     bf16[128][256]
    //   cursor : 5308416  (+16384)     (becomes cnt_i after k_pre)
    //   deg    : 5324800  (+16384)     -> end 5341184 (~5.3 MB)
    char* ws = (char*)d_ws;
    unsigned short* xT     = (unsigned short*)(ws);
    unsigned short* elist  = (unsigned short*)(ws + 4194304);
    unsigned short* WTb    = (unsigned short*)(ws + 5242880);
    int*            cursor = (int*)(ws + 5308416);
    int*            deg    = (int*)(ws + 5324800);

    // Zero cursor + deg (contiguous 32 KB)
    hipMemsetAsync(cursor, 0, 32768, stream);

    k_pre<<<2688, 256, 0, stream>>>(x, xT, W, WTb, idx_i, idx_j, cursor, elist, deg);
    k_final<<<dim3(NN / 32, BATCH), 256, 0, stream>>>(xT, WTb, bias, elist, cursor, deg, out);
}

// Round 6
// 105.156 us; speedup vs baseline: 9.5242x; 1.1252x over previous
//
#include <hip/hip_runtime.h>
#include <cstdint>
#include <cstddef>

// Problem constants (PairwiseConv_22488448761917)
#define BATCH   4
#define CIN     128
#define NN      4096
#define EE      131072
#define CCONV   127      // C_OUT - 1
#define NBC     512      // B*C elements per node row in (N,B,C) layout
#define MAXDEG  128      // ELL row capacity; deg ~ Bin(131072,1/4096), P(>128) ~ e^-81
#define CPAD    16       // counter padding: one int per 64B cacheline

typedef __attribute__((ext_vector_type(8))) short short8;            // 8 bf16
typedef __attribute__((ext_vector_type(8))) unsigned short ushort8;  // 8 bf16 bits
typedef __attribute__((ext_vector_type(4))) float f32x4;             // MFMA C/D frag

__device__ __forceinline__ unsigned short f2bf(float f) {
    unsigned int u = __float_as_uint(f);
    return (unsigned short)((u + 0x7FFFu + ((u >> 16) & 1u)) >> 16);
}
__device__ __forceinline__ float bf2f(unsigned short h) {
    return __uint_as_float((unsigned int)h << 16);
}

// ---------------------------------------------------------------------------
// K1 (fused pre):
//   blocks [0,2048)    : transpose x (B,C,N) fp32 -> xT (N,B,C) bf16
//   blocks [2048,2560) : ELL build: elist[ni*128+pos]=nj; cursor/deg atomics
//                        on CACHELINE-PADDED counters (idx*16) to kill
//                        same-line L2 atomic serialization.
//   blocks [2560,2688) : WTb[o][k] bf16 weight repack
// ---------------------------------------------------------------------------
__global__ __launch_bounds__(256) void k_pre(const float* __restrict__ x,
                                             unsigned short* __restrict__ xT,
                                             const float* __restrict__ W,
                                             unsigned short* __restrict__ WTb,
                                             const int* __restrict__ idx_i,
                                             const int* __restrict__ idx_j,
                                             int* __restrict__ cursor,
                                             unsigned short* __restrict__ elist,
                                             int* __restrict__ deg) {
    const int bid = blockIdx.x;
    const int tid = threadIdx.x;
    if (bid < 2048) {
        __shared__ float tile[32][33];
        const int nb = bid & 127;
        const int cb = (bid >> 7) & 3;
        const int b  = bid >> 9;
        const int n0 = nb * 32, c0 = cb * 32;
        const int tx = tid & 31, ty = tid >> 5;   // 32 x 8
        const float* xb = x + (size_t)b * CIN * NN;
#pragma unroll
        for (int i = 0; i < 4; ++i)
            tile[ty + i * 8][tx] = xb[(size_t)(c0 + ty + i * 8) * NN + n0 + tx];
        __syncthreads();
#pragma unroll
        for (int i = 0; i < 4; ++i) {
            const int nl = ty + i * 8;
            xT[(size_t)(n0 + nl) * NBC + b * CIN + c0 + tx] = f2bf(tile[tx][nl]);
        }
    } else if (bid < 2560) {
        const int e  = (bid - 2048) * 256 + tid;
        const int ni = idx_i[e];
        const int nj = idx_j[e];
        const int pos = atomicAdd(&cursor[ni * CPAD], 1);
        elist[(size_t)ni * MAXDEG + pos] = (unsigned short)nj;
        atomicAdd(&deg[nj * CPAD], 1);
    } else {
        const int t = (bid - 2560) * 256 + tid;   // < 128*256
        const int o = t >> 8;
        const int k = t & 255;
        float v = 0.0f;
        if (o < CCONV) v = W[((size_t)o * CIN + (k & 127)) * 2 + (k >> 7)];
        WTb[t] = f2bf(v);
    }
}

// ---------------------------------------------------------------------------
// K2 (final, fused gather-agg + MFMA GEMM + epilogue):
//   Block = (16-node tile) x (batch b); grid 256x4 = 1024 blocks (4/CU).
//   Phase A: gather-agg. Wave w handles nodes j=w*4+ns (ns=lane>>4);
//     16 lanes/node x 8ch ushort8. Edge loop in groups of 8: one ushort8
//     index load, then 8 INDEPENDENT row gathers (8 outstanding loads/lane),
//     fp32 accumulate, bf16 pack straight into LDS A-frag slots kt=4..7.
//   Phase B: x-part (kt 0..3): Z = xT * cnt, A-frag order (conflict-free).
//   Phase C: MFMA 16x16x32 bf16: M=16(j) x N=128(o) x K=256.
//     B from global WTb[o][k] (64 KB, L2-hot).
//     D layout (m89): col(o)=lane&15, row(j)=(lane>>4)*4+reg.
//   Phase D: epilogue (cnt*bias, /deg) + ch127 = deg row.
// ---------------------------------------------------------------------------
__global__ __launch_bounds__(256) void k_final(const unsigned short* __restrict__ xT,
                                               const unsigned short* __restrict__ WTb,
                                               const float* __restrict__ bias,
                                               const unsigned short* __restrict__ elist,
                                               const int* __restrict__ cnt_i,
                                               const int* __restrict__ deg,
                                               float* __restrict__ out) {
    __shared__ short Af[512 * 8];           // 8 KB: 8 kt x 64 lane x 16 B
    __shared__ float cntf[16], invd[16], degf[16], biasf[128];
    __shared__ int   cnti[16];

    const int tid = threadIdx.x;
    const int b   = blockIdx.y;
    const int n0  = blockIdx.x * 16;

    if (tid < 16) {
        const int c = cnt_i[(n0 + tid) * CPAD];
        const int d = deg[(n0 + tid) * CPAD];
        cnti[tid] = c;
        cntf[tid] = (float)c;
        degf[tid] = (float)d;
        invd[tid] = (d == 0) ? 1.0f : 1.0f / (float)d;
    } else if (tid >= 64 && tid < 192) {
        const int o = tid - 64;
        biasf[o] = (o < CCONV) ? bias[o] : 0.0f;
    }
    __syncthreads();

    const int lane = tid & 63;
    const int w    = tid >> 6;

    // ---- Phase A: gather-agg -> A-frag slots kt 4..7 ----
    {
        const int ns = lane >> 4;           // node within wave's group of 4
        const int j  = w * 4 + ns;          // 0..15
        const int c0 = (lane & 15) * 8;     // channel base (8 ch per lane)
        const unsigned short* xb = xT + b * CIN + c0;
        const int dn = cnti[j];
        const unsigned short* erow = elist + (size_t)(n0 + j) * MAXDEG;
        float acc[8] = {0, 0, 0, 0, 0, 0, 0, 0};
        int k = 0;
        for (; k + 8 <= dn; k += 8) {
            const ushort8 i8 = *(const ushort8*)(erow + k);   // 8 edge indices
            ushort8 u[8];
#pragma unroll
            for (int t = 0; t < 8; ++t)                        // 8 outstanding
                u[t] = *(const ushort8*)(xb + (size_t)i8[t] * NBC);
#pragma unroll
            for (int t = 0; t < 8; ++t)
#pragma unroll
                for (int q = 0; q < 8; ++q) acc[q] += bf2f(u[t][q]);
        }
        for (; k < dn; ++k) {
            const ushort8 u = *(const ushort8*)(xb + (size_t)erow[k] * NBC);
#pragma unroll
            for (int q = 0; q < 8; ++q) acc[q] += bf2f(u[q]);
        }
        short8 p;
#pragma unroll
        for (int q = 0; q < 8; ++q) p[q] = (short)f2bf(acc[q]);
        // k_global = 128 + c0 -> kt = 4 + (c0>>5), g = (c0>>3)&3
        const int kt   = 4 + (c0 >> 5);
        const int g    = (c0 >> 3) & 3;
        const int unit = kt * 64 + 16 * g + j;
        *(short8*)&Af[unit * 8] = p;
    }

    // ---- Phase B: x-part staging (kt 0..3), 256 units / 256 threads ----
    {
        const int L  = tid & 63;
        const int kt = tid >> 6;            // 0..3
        const int j  = L & 15;
        const int k0 = kt * 32 + (L >> 4) * 8;
        const short8 a = *(const short8*)(xT + (size_t)(n0 + j) * NBC + b * CIN + k0);
        const float sc = cntf[j];
        short8 p;
#pragma unroll
        for (int q = 0; q < 8; ++q)
            p[q] = (short)f2bf(bf2f((unsigned short)a[q]) * sc);
        *(short8*)&Af[(kt * 64 + L) * 8] = p;
    }
    __syncthreads();

    // ---- Phase C: MFMA ----
    const int m = lane & 15;
    const int g = lane >> 4;

    f32x4 acc0 = (f32x4){0.0f, 0.0f, 0.0f, 0.0f};
    f32x4 acc1 = (f32x4){0.0f, 0.0f, 0.0f, 0.0f};

    const unsigned short* B0 = WTb + (size_t)(w * 32 + m) * 256;
    const unsigned short* B1 = B0 + 16 * 256;

#pragma unroll
    for (int kt = 0; kt < 8; ++kt) {
        const int k0 = kt * 32 + g * 8;
        const short8 b0 = *(const short8*)(B0 + k0);
        const short8 b1 = *(const short8*)(B1 + k0);
        const short8 a  = *(const short8*)&Af[(kt * 64 + lane) * 8];
        acc0 = __builtin_amdgcn_mfma_f32_16x16x32_bf16(a, b0, acc0, 0, 0, 0);
        acc1 = __builtin_amdgcn_mfma_f32_16x16x32_bf16(a, b1, acc1, 0, 0, 0);
    }

    // ---- Phase D: epilogue ----
#pragma unroll
    for (int nt = 0; nt < 2; ++nt) {
        const f32x4 a = nt ? acc1 : acc0;
        const int o = w * 32 + nt * 16 + m;
        if (o >= CCONV) continue;   // o==127 handled below
        const float bo = biasf[o];
        float* orow = out + ((size_t)b * 128 + o) * NN + n0;
        const int j0 = g * 4;
        float4 r;
        r.x = (a[0] + cntf[j0 + 0] * bo) * invd[j0 + 0];
        r.y = (a[1] + cntf[j0 + 1] * bo) * invd[j0 + 1];
        r.z = (a[2] + cntf[j0 + 2] * bo) * invd[j0 + 2];
        r.w = (a[3] + cntf[j0 + 3] * bo) * invd[j0 + 3];
        *(float4*)(orow + j0) = r;
    }
    // fused ch127: out[b][127][n] = deg[n]
    if (tid < 16)
        out[((size_t)b * 128 + CCONV) * NN + n0 + tid] = degf[tid];
}

// ---------------------------------------------------------------------------
extern "C" void kernel_launch(void* const* d_in, const int* in_sizes, int n_in,
                              void* d_out, int out_size, void* d_ws, size_t ws_size,
                              hipStream_t stream) {
    const float* x    = (const float*)d_in[0];
    const float* W    = (const float*)d_in[1];
    const float* bias = (const float*)d_in[2];
    const int* idx_i  = (const int*)d_in[3];
    const int* idx_j  = (const int*)d_in[4];
    float* out = (float*)d_out;

    // Workspace layout (bytes):
    //   xT     : 0        (+4194304)   bf16 (N,B,C)
    //   elist  : 4194304  (+1048576)   ushort[N][128] ELL
    //   WTb    : 5242880  (+65536)     bf16[128][256]
    //   cursor : 5308416  (+262144)    int[N*16] padded (becomes cnt_i)
    //   deg    : 5570560  (+262144)    int[N*16] padded  -> end 5832704
    char* ws = (char*)d_ws;
    unsigned short* xT     = (unsigned short*)(ws);
    unsigned short* elist  = (unsigned short*)(ws + 4194304);
    unsigned short* WTb    = (unsigned short*)(ws + 5242880);
    int*            cursor = (int*)(ws + 5308416);
    int*            deg    = (int*)(ws + 5570560);

    // Zero cursor + deg (contiguous 512 KB)
    hipMemsetAsync(cursor, 0, 524288, stream);

    k_pre<<<2688, 256, 0, stream>>>(x, xT, W, WTb, idx_i, idx_j, cursor, elist, deg);
    k_final<<<dim3(NN / 16, BATCH), 256, 0, stream>>>(xT, WTb, bias, elist, cursor, deg, out);
}

// Round 8
// 101.382 us; speedup vs baseline: 9.8787x; 1.0372x over previous
//
#include <hip/hip_runtime.h>
#include <cstdint>
#include <cstddef>

// Problem constants (PairwiseConv_22488448761917)
#define BATCH   4
#define CIN     128
#define NN      4096
#define EE      131072
#define CCONV   127      // C_OUT - 1
#define NBC     512      // B*C elements per node row in (N,B,C) layout
#define MAXDEG  128      // ELL row capacity; deg ~ Bin(131072,1/4096), P(>128) ~ e^-81
#define CPAD    16       // counter padding: one int per 64B cacheline

typedef __attribute__((ext_vector_type(8))) short short8;            // 8 bf16
typedef __attribute__((ext_vector_type(8))) unsigned short ushort8;  // 8 bf16 bits
typedef __attribute__((ext_vector_type(4))) float f32x4;             // MFMA C/D frag

__device__ __forceinline__ unsigned short f2bf(float f) {
    unsigned int u = __float_as_uint(f);
    return (unsigned short)((u + 0x7FFFu + ((u >> 16) & 1u)) >> 16);
}
__device__ __forceinline__ float bf2f(unsigned short h) {
    return __uint_as_float((unsigned int)h << 16);
}

// ---------------------------------------------------------------------------
// K1 (fused pre):
//   blocks [0,256)   : transpose x (B,C,N) fp32 -> xT (N,B,C) bf16.
//     64-node x 128-ch tile; LDS fp32 [128][65] (stride 65: write 2-way-free,
//     read-out 4-way, negligible). Output written as FULL 256 B node rows
//     (64 lanes x ushort2) -- fixes R6's 64 B fragment writes.
//   blocks [256,768) : ELL build: elist[ni*128+pos]=nj; padded-counter atomics.
//   blocks [768,896) : WTb[o][k] bf16 weight repack.
// ---------------------------------------------------------------------------
__global__ __launch_bounds__(256) void k_pre(const float* __restrict__ x,
                                             unsigned short* __restrict__ xT,
                                             const float* __restrict__ W,
                                             unsigned short* __restrict__ WTb,
                                             const int* __restrict__ idx_i,
                                             const int* __restrict__ idx_j,
                                             int* __restrict__ cursor,
                                             unsigned short* __restrict__ elist,
                                             int* __restrict__ deg) {
    const int bid = blockIdx.x;
    const int tid = threadIdx.x;
    if (bid < 256) {
        __shared__ float tile[128][65];
        const int b  = bid & 3;
        const int n0 = (bid >> 2) * 64;
        // read: 128 c-rows x 64 floats; 16 rows x 16 lanes(float4) per iter
        const int rl = tid >> 4;       // row within group (0..15)
        const int l4 = (tid & 15) * 4; // float4 offset within row
        const float* xb = x + (size_t)b * CIN * NN + n0 + l4;
#pragma unroll
        for (int it = 0; it < 8; ++it) {
            const int c = it * 16 + rl;
            const float4 v = *(const float4*)(xb + (size_t)c * NN);
            tile[c][l4 + 0] = v.x;
            tile[c][l4 + 1] = v.y;
            tile[c][l4 + 2] = v.z;
            tile[c][l4 + 3] = v.w;
        }
        __syncthreads();
        // write: 64 node-rows x 256 B; 4 nodes x 64 lanes(ushort2) per iter
        const int l = tid & 63;
#pragma unroll
        for (int it = 0; it < 16; ++it) {
            const int n = it * 4 + (tid >> 6);
            ushort2 r;
            r.x = f2bf(tile[2 * l + 0][n]);
            r.y = f2bf(tile[2 * l + 1][n]);
            *(ushort2*)(xT + (size_t)(n0 + n) * NBC + b * CIN + 2 * l) = r;
        }
    } else if (bid < 768) {
        const int e  = (bid - 256) * 256 + tid;
        const int ni = idx_i[e];
        const int nj = idx_j[e];
        const int pos = atomicAdd(&cursor[ni * CPAD], 1);
        elist[(size_t)ni * MAXDEG + pos] = (unsigned short)nj;
        atomicAdd(&deg[nj * CPAD], 1);
    } else {
        const int t = (bid - 768) * 256 + tid;    // < 128*256
        const int o = t >> 8;
        const int k = t & 255;
        float v = 0.0f;
        if (o < CCONV) v = W[((size_t)o * CIN + (k & 127)) * 2 + (k >> 7)];
        WTb[t] = f2bf(v);
    }
}

// ---------------------------------------------------------------------------
// K2 (final, fused gather-agg + MFMA GEMM + epilogue):
//   Block = (16-node tile) x (batch b); grid 256x4 = 1024 blocks (4/CU).
//   Phase A: gather-agg, 8-deep load ILP, fp32 accumulate, bf16 pack into
//     LDS A-frag slots kt=4..7.
//   Phase B: x-part (kt 0..3): Z = xT * cnt, A-frag order (conflict-free).
//   Phase C: MFMA 16x16x32 bf16: M=16(j) x N=128(o) x K=256.
//     B from global WTb[o][k] (64 KB, L2-hot).
//     D layout (m89): col(o)=lane&15, row(j)=(lane>>4)*4+reg.
//   Phase D: epilogue (cnt*bias, /deg) + ch127 = deg row.
// ---------------------------------------------------------------------------
__global__ __launch_bounds__(256) void k_final(const unsigned short* __restrict__ xT,
                                               const unsigned short* __restrict__ WTb,
                                               const float* __restrict__ bias,
                                               const unsigned short* __restrict__ elist,
                                               const int* __restrict__ cnt_i,
                                               const int* __restrict__ deg,
                                               float* __restrict__ out) {
    __shared__ short Af[512 * 8];           // 8 KB: 8 kt x 64 lane x 16 B
    __shared__ float cntf[16], invd[16], degf[16], biasf[128];
    __shared__ int   cnti[16];

    const int tid = threadIdx.x;
    const int b   = blockIdx.y;
    const int n0  = blockIdx.x * 16;

    if (tid < 16) {
        const int c = cnt_i[(n0 + tid) * CPAD];
        const int d = deg[(n0 + tid) * CPAD];
        cnti[tid] = c;
        cntf[tid] = (float)c;
        degf[tid] = (float)d;
        invd[tid] = (d == 0) ? 1.0f : 1.0f / (float)d;
    } else if (tid >= 64 && tid < 192) {
        const int o = tid - 64;
        biasf[o] = (o < CCONV) ? bias[o] : 0.0f;
    }
    __syncthreads();

    const int lane = tid & 63;
    const int w    = tid >> 6;

    // ---- Phase A: gather-agg -> A-frag slots kt 4..7 ----
    {
        const int ns = lane >> 4;           // node within wave's group of 4
        const int j  = w * 4 + ns;          // 0..15
        const int c0 = (lane & 15) * 8;     // channel base (8 ch per lane)
        const unsigned short* xb = xT + b * CIN + c0;
        const int dn = cnti[j];
        const unsigned short* erow = elist + (size_t)(n0 + j) * MAXDEG;
        float acc[8] = {0, 0, 0, 0, 0, 0, 0, 0};
        int k = 0;
        for (; k + 8 <= dn; k += 8) {
            const ushort8 i8 = *(const ushort8*)(erow + k);   // 8 edge indices
            ushort8 u[8];
#pragma unroll
            for (int t = 0; t < 8; ++t)                        // 8 outstanding
                u[t] = *(const ushort8*)(xb + (size_t)i8[t] * NBC);
#pragma unroll
            for (int t = 0; t < 8; ++t)
#pragma unroll
                for (int q = 0; q < 8; ++q) acc[q] += bf2f(u[t][q]);
        }
        for (; k < dn; ++k) {
            const ushort8 u = *(const ushort8*)(xb + (size_t)erow[k] * NBC);
#pragma unroll
            for (int q = 0; q < 8; ++q) acc[q] += bf2f(u[q]);
        }
        short8 p;
#pragma unroll
        for (int q = 0; q < 8; ++q) p[q] = (short)f2bf(acc[q]);
        const int kt   = 4 + (c0 >> 5);
        const int g    = (c0 >> 3) & 3;
        const int unit = kt * 64 + 16 * g + j;
        *(short8*)&Af[unit * 8] = p;
    }

    // ---- Phase B: x-part staging (kt 0..3), 256 units / 256 threads ----
    {
        const int L  = tid & 63;
        const int kt = tid >> 6;            // 0..3
        const int j  = L & 15;
        const int k0 = kt * 32 + (L >> 4) * 8;
        const short8 a = *(const short8*)(xT + (size_t)(n0 + j) * NBC + b * CIN + k0);
        const float sc = cntf[j];
        short8 p;
#pragma unroll
        for (int q = 0; q < 8; ++q)
            p[q] = (short)f2bf(bf2f((unsigned short)a[q]) * sc);
        *(short8*)&Af[(kt * 64 + L) * 8] = p;
    }
    __syncthreads();

    // ---- Phase C: MFMA ----
    const int m = lane & 15;
    const int g = lane >> 4;

    f32x4 acc0 = (f32x4){0.0f, 0.0f, 0.0f, 0.0f};
    f32x4 acc1 = (f32x4){0.0f, 0.0f, 0.0f, 0.0f};

    const unsigned short* B0 = WTb + (size_t)(w * 32 + m) * 256;
    const unsigned short* B1 = B0 + 16 * 256;

#pragma unroll
    for (int kt = 0; kt < 8; ++kt) {
        const int k0 = kt * 32 + g * 8;
        const short8 b0 = *(const short8*)(B0 + k0);
        const short8 b1 = *(const short8*)(B1 + k0);
        const short8 a  = *(const short8*)&Af[(kt * 64 + lane) * 8];
        acc0 = __builtin_amdgcn_mfma_f32_16x16x32_bf16(a, b0, acc0, 0, 0, 0);
        acc1 = __builtin_amdgcn_mfma_f32_16x16x32_bf16(a, b1, acc1, 0, 0, 0);
    }

    // ---- Phase D: epilogue ----
#pragma unroll
    for (int nt = 0; nt < 2; ++nt) {
        const f32x4 a = nt ? acc1 : acc0;
        const int o = w * 32 + nt * 16 + m;
        if (o >= CCONV) continue;   // o==127 handled below
        const float bo = biasf[o];
        float* orow = out + ((size_t)b * 128 + o) * NN + n0;
        const int j0 = g * 4;
        float4 r;
        r.x = (a[0] + cntf[j0 + 0] * bo) * invd[j0 + 0];
        r.y = (a[1] + cntf[j0 + 1] * bo) * invd[j0 + 1];
        r.z = (a[2] + cntf[j0 + 2] * bo) * invd[j0 + 2];
        r.w = (a[3] + cntf[j0 + 3] * bo) * invd[j0 + 3];
        *(float4*)(orow + j0) = r;
    }
    // fused ch127: out[b][127][n] = deg[n]
    if (tid < 16)
        out[((size_t)b * 128 + CCONV) * NN + n0 + tid] = degf[tid];
}

// ---------------------------------------------------------------------------
extern "C" void kernel_launch(void* const* d_in, const int* in_sizes, int n_in,
                              void* d_out, int out_size, void* d_ws, size_t ws_size,
                              hipStream_t stream) {
    const float* x    = (const float*)d_in[0];
    const float* W    = (const float*)d_in[1];
    const float* bias = (const float*)d_in[2];
    const int* idx_i  = (const int*)d_in[3];
    const int* idx_j  = (const int*)d_in[4];
    float* out = (float*)d_out;

    // Workspace layout (bytes):
    //   xT     : 0        (+4194304)   bf16 (N,B,C)
    //   elist  : 4194304  (+1048576)   ushort[N][128] ELL
    //   WTb    : 5242880  (+65536)     bf16[128][256]
    //   cursor : 5308416  (+262144)    int[N*16] padded (becomes cnt_i)
    //   deg    : 5570560  (+262144)    int[N*16] padded  -> end 5832704
    char* ws = (char*)d_ws;
    unsigned short* xT     = (unsigned short*)(ws);
    unsigned short* elist  = (unsigned short*)(ws + 4194304);
    unsigned short* WTb    = (unsigned short*)(ws + 5242880);
    int*            cursor = (int*)(ws + 5308416);
    int*            deg    = (int*)(ws + 5570560);

    // Zero cursor + deg (contiguous 512 KB)
    hipMemsetAsync(cursor, 0, 524288, stream);

    k_pre<<<896, 256, 0, stream>>>(x, xT, W, WTb, idx_i, idx_j, cursor, elist, deg);
    k_final<<<dim3(NN / 16, BATCH), 256, 0, stream>>>(xT, WTb, bias, elist, cursor, deg, out);
}